// Round 10
// baseline (218.549 us; speedup 1.0000x reference)
//
#include <hip/hip_runtime.h>
#include <hip/hip_bf16.h>
#include <stdint.h>

// ---------------------------------------------------------------------------
// SSD (Mamba-2 chunked scan) B=2, L=4096, DM=1024, NH=32, HD=32, DS=64, CS=256
// R10: gemm = R8 verbatim (BK=32 64x128; R9's BK=64 was neutral-time with
// worse FETCH/occupancy). y_kernel and middle_kernel process 2 heads per
// block: the 32KB bc-dependent LDS stage (Bbf / BbfT) is loaded once and
// reused across both heads (halves staging traffic + block count).
// ---------------------------------------------------------------------------

typedef __bf16 bf16x8 __attribute__((ext_vector_type(8)));
typedef __bf16 bf16x4 __attribute__((ext_vector_type(4)));
typedef float  f32x4  __attribute__((ext_vector_type(4)));

#define MFMA16(a, b, c) __builtin_amdgcn_mfma_f32_16x16x32_bf16((a), (b), (c), 0, 0, 0)

__device__ __forceinline__ void async_copy16(const __bf16* g, __bf16* l) {
    __builtin_amdgcn_global_load_lds((const __attribute__((address_space(1))) void*)g,
                                     (__attribute__((address_space(3))) void*)l,
                                     16, 0, 0);
}

// ---------------------------------------------------------------------------
// fused fp32->bf16 convert for u, W_in, W_out
// ---------------------------------------------------------------------------
__global__ void cvt_all(const float* __restrict__ u, __bf16* __restrict__ ub,
                        const float* __restrict__ wi, __bf16* __restrict__ wib,
                        const float* __restrict__ wo, __bf16* __restrict__ wob)
{
    long i = ((long)blockIdx.x * 256 + threadIdx.x) * 4;
    const float* src; __bf16* dst; long off;
    if (i < 8388608)        { src = u;  dst = ub;  off = i; }
    else if (i < 9601024)   { src = wi; dst = wib; off = i - 8388608; }
    else if (i < 10649600)  { src = wo; dst = wob; off = i - 9601024; }
    else return;
    float4 v = *(const float4*)(src + off);
    bf16x4 o;
    o[0] = (__bf16)v.x; o[1] = (__bf16)v.y; o[2] = (__bf16)v.z; o[3] = (__bf16)v.w;
    *(bf16x4*)(dst + off) = o;
}

// ---------------------------------------------------------------------------
// GEMM core: 64M x 128N tile, BK=32 (R8 verbatim — measured 40.9us, 18MB
// FETCH, 39% occupancy, ~0 conflicts).
// ---------------------------------------------------------------------------
__global__ __launch_bounds__(256) void gemm_fused(
    const __bf16* __restrict__ A, const __bf16* __restrict__ Bt,
    int K, int Nrows, int mode,
    float* __restrict__ Cout, __bf16* __restrict__ xbf,
    __bf16* __restrict__ Bbf, __bf16* __restrict__ Cbf,
    __bf16* __restrict__ BbfT, float* __restrict__ dtz)
{
    __shared__ __attribute__((aligned(16))) __bf16 smem[6144];
    __bf16* As = smem;            // 64*32 = 2048
    __bf16* Bs = smem + 2048;     // 128*32 = 4096
    const int tid = threadIdx.x;
    const int m0 = blockIdx.x * 64;        // M-fast: same-A blocks share XCD
    const int n0 = blockIdx.y * 128;
    const int w = tid >> 6, lane = tid & 63;
    const int fr = lane & 15, quad = lane >> 4;
    const int sw = quad ^ ((fr >> 1) & 3);         // fragment-read position

    const int lr  = lane >> 2;                      // row within 16-row group
    const int lc8 = (((lane & 3) ^ ((lane >> 3) & 3))) * 8;  // swizzled chunk
    const int ra  = m0 + w * 16 + lr;               // A: wave stages 16 rows
    const int rb0 = min(n0 + w * 32 + lr, Nrows - 1);
    const int rb1 = min(n0 + w * 32 + 16 + lr, Nrows - 1);
    const __bf16* aP  = A + (size_t)ra * K + lc8;
    const __bf16* bP0 = Bt + (size_t)rb0 * K + lc8;
    const __bf16* bP1 = Bt + (size_t)rb1 * K + lc8;
    __bf16* dA  = As + w * 512;
    __bf16* dB0 = Bs + w * 1024;
    __bf16* dB1 = Bs + w * 1024 + 512;

    f32x4 acc[4][2] = {};

    for (int kt = 0; kt < K; kt += 32) {
        async_copy16(aP + kt, dA);
        async_copy16(bP0 + kt, dB0);
        async_copy16(bP1 + kt, dB1);
        __syncthreads();
        bf16x8 af[4], bfv[2];
#pragma unroll
        for (int a = 0; a < 4; ++a)
            af[a] = *(const bf16x8*)&As[(a * 16 + fr) * 32 + sw * 8];
#pragma unroll
        for (int b = 0; b < 2; ++b)
            bfv[b] = *(const bf16x8*)&Bs[(w * 32 + b * 16 + fr) * 32 + sw * 8];
#pragma unroll
        for (int a = 0; a < 4; ++a)
#pragma unroll
            for (int b = 0; b < 2; ++b)
                acc[a][b] = MFMA16(af[a], bfv[b], acc[a][b]);
        __syncthreads();
    }

    const int rowb = quad * 4;
    if (mode == 0) {
#pragma unroll
        for (int a = 0; a < 4; ++a)
#pragma unroll
            for (int b = 0; b < 2; ++b) {
                int col = n0 + w * 32 + b * 16 + fr;
#pragma unroll
                for (int q = 0; q < 4; ++q) {
                    int row = m0 + a * 16 + rowb + q;
                    Cout[(size_t)row * 1024 + col] = acc[a][b][q];
                }
            }
    } else if (blockIdx.y < 8) {
#pragma unroll
        for (int a = 0; a < 4; ++a)
#pragma unroll
            for (int b = 0; b < 2; ++b) {
                int col = n0 + w * 32 + b * 16 + fr;
#pragma unroll
                for (int q = 0; q < 4; ++q) {
                    int row = m0 + a * 16 + rowb + q;
                    xbf[(size_t)row * 1024 + col] = (__bf16)acc[a][b][q];
                }
            }
    } else if (blockIdx.y == 8) {
        // B/C routing + LDS-transposed coalesced BbfT (64 n x 64 rows)
        __bf16* Btile = smem;   // 64 x 72 (K-loop done; smem free)
#pragma unroll
        for (int a = 0; a < 4; ++a)
#pragma unroll
            for (int b = 0; b < 2; ++b) {
                int cl = w * 32 + b * 16 + fr;
#pragma unroll
                for (int q = 0; q < 4; ++q) {
                    int row = m0 + a * 16 + rowb + q;
                    __bf16 v = (__bf16)acc[a][b][q];
                    if (cl < 64) {
                        Bbf[(size_t)row * 64 + cl] = v;
                        Btile[cl * 72 + (row - m0)] = v;
                    } else {
                        Cbf[(size_t)row * 64 + cl - 64] = v;
                    }
                }
            }
        __syncthreads();
        const size_t bcb = (size_t)(m0 >> 8) * 16384 + (m0 & 255);
        int n = tid >> 2, g = tid & 3;
#pragma unroll
        for (int it = 0; it < 2; ++it) {
            int jl = g * 16 + it * 8;
            bf16x8 v = *(const bf16x8*)&Btile[n * 72 + jl];
            *(bf16x8*)&BbfT[bcb + (size_t)n * 256 + jl] = v;
        }
    } else {
#pragma unroll
        for (int a = 0; a < 4; ++a)
#pragma unroll
            for (int b = 0; b < 2; ++b) {
                int cl = w * 32 + b * 16 + fr;
                if (cl < 32) {
#pragma unroll
                    for (int q = 0; q < 4; ++q) {
                        int row = m0 + a * 16 + rowb + q;
                        dtz[(size_t)row * 32 + cl] = acc[a][b][q];
                    }
                }
            }
    }
}

// ---------------------------------------------------------------------------
// middle: fused prep + xdtT + states, 2 heads per block (BbfT staged once).
// ---------------------------------------------------------------------------
__global__ __launch_bounds__(256) void middle_kernel(
    const float* __restrict__ dtz, const float* __restrict__ dt_bias,
    const float* __restrict__ A_log, const __bf16* __restrict__ xbf,
    const __bf16* __restrict__ BbfT,
    float* __restrict__ acum_out, __bf16* __restrict__ xdtT,
    float* __restrict__ states)
{
    const int h2 = blockIdx.x, c = blockIdx.y, b = blockIdx.z;
    const size_t bc = (size_t)b * 16 + c;
    __shared__ __bf16 tile[256][33];
    __shared__ __attribute__((aligned(16))) __bf16 xdecT[32 * 264];
    __shared__ __attribute__((aligned(16))) __bf16 Bsh2[64 * 256];
    __shared__ float dts[256], decs[256], wsum[4];
    const int t = threadIdx.x, wave = t >> 6, lane = t & 63;

    {   // stage BbfT[bc] once (32 KB), chunk-swizzled: pos p holds chunk p^(n&7)
        const __bf16* src = BbfT + bc * 16384;
#pragma unroll
        for (int cc = 0; cc < 8; ++cc) {
            int s = wave * 8 + cc;
            int n = s * 2 + (lane >> 5);
            int jc = (lane & 31) ^ (n & 7);
            async_copy16(src + n * 256 + jc * 8, Bsh2 + s * 512);
        }
    }

    for (int hh = 0; hh < 2; ++hh) {
        const int h = h2 * 2 + hh;
        const size_t bch = bc * 32 + h;

        float z = dtz[(bc * 256 + t) * 32 + h] + dt_bias[h];
        float dtv = (z > 20.f) ? z : log1pf(expf(z));
        float Av = -expf(A_log[h]);
        float val = dtv * Av;
        dts[t] = dtv;
#pragma unroll
        for (int off = 1; off < 64; off <<= 1) {
            float nv = __shfl_up(val, off, 64);
            if (lane >= off) val += nv;
        }
        if (lane == 63) wsum[wave] = val;
        __syncthreads();            // also drains Bsh2 staging on hh=0
        float basep = 0.f, tot = 0.f;
#pragma unroll
        for (int wv = 0; wv < 4; ++wv) {
            float s = wsum[wv];
            if (wv < wave) basep += s;
            tot += s;
        }
        val += basep;
        acum_out[bch * 256 + t] = val;
        decs[t] = __expf(tot - val);

#pragma unroll
        for (int it = 0; it < 4; ++it) {
            int id = it * 256 + t;
            int j = id >> 2, pg = id & 3;
            bf16x8 v = *(const bf16x8*)&xbf[(bc * 256 + j) * 1024 + h * 32 + pg * 8];
            float d = dts[j];
#pragma unroll
            for (int e = 0; e < 8; ++e) tile[j][pg * 8 + e] = (__bf16)((float)v[e] * d);
        }
        __syncthreads();

#pragma unroll
        for (int it = 0; it < 4; ++it) {
            int id = it * 256 + t;
            int p = id >> 5, jg = id & 31;
            bf16x8 o, od;
#pragma unroll
            for (int e = 0; e < 8; ++e) {
                __bf16 v = tile[jg * 8 + e][p];
                o[e] = v;
                od[e] = (__bf16)((float)v * decs[jg * 8 + e]);
            }
            *(bf16x8*)&xdtT[bch * 8192 + p * 256 + jg * 8] = o;
            *(bf16x8*)&xdecT[p * 264 + jg * 8] = od;
        }
        __syncthreads();

        const int fr = lane & 15, quad = lane >> 4, fk = quad * 8;
        const int mt = wave >> 1, ntb = (wave & 1) * 2;
        f32x4 acc[2] = {};
#pragma unroll
        for (int ks = 0; ks < 8; ++ks) {
            bf16x8 af = *(const bf16x8*)&xdecT[(mt * 16 + fr) * 264 + ks * 32 + fk];
#pragma unroll
            for (int nb = 0; nb < 2; ++nb) {
                int n = (ntb + nb) * 16 + fr;
                int ch = (ks * 4 + quad) ^ (n & 7);
                bf16x8 bfv = *(const bf16x8*)&Bsh2[n * 256 + ch * 8];
                acc[nb] = MFMA16(af, bfv, acc[nb]);
            }
        }
        const int rowb = quad * 4;
#pragma unroll
        for (int nb = 0; nb < 2; ++nb)
#pragma unroll
            for (int q = 0; q < 4; ++q) {
                int p = mt * 16 + rowb + q;
                int n = (ntb + nb) * 16 + fr;
                states[bch * 2048 + p * 64 + n] = acc[nb][q];
            }
        __syncthreads();            // protect tile/dts/decs/wsum/xdecT reuse
    }
}

// ---------------------------------------------------------------------------
// scan: prev[b,c] = prev[b,c-1]*exp(alast[c-1]) + states[c-1]; bf16 out.
// ---------------------------------------------------------------------------
__global__ void scan_kernel(const float* __restrict__ states,
                            const float* __restrict__ acum,
                            __bf16* __restrict__ prevbf)
{
    int t = blockIdx.x * 256 + threadIdx.x;
    int n = t & 63, p = (t >> 6) & 31, h = (t >> 11) & 31, b = t >> 16;
    float s = 0.f;
    for (int c = 0; c < 16; ++c) {
        size_t bch = ((size_t)(b * 16 + c) * 32 + h);
        size_t off = bch * 2048 + (size_t)p * 64 + n;
        prevbf[off] = (__bf16)s;
        float dec = __expf(acum[bch * 256 + 255]);
        s = s * dec + states[off];
    }
}

// ---------------------------------------------------------------------------
// y: block=(bc, h-pair); Bsh staged once, per-head xsh/ash restaged; the h1
// staging is issued after the post-jt barrier so it overlaps h0's epilogue.
// ---------------------------------------------------------------------------
__global__ __launch_bounds__(256, 2) void y_kernel(
    const __bf16* __restrict__ Bbf, const __bf16* __restrict__ Cbf,
    const float* __restrict__ acum, const __bf16* __restrict__ xdtT,
    const __bf16* __restrict__ prevbf, const __bf16* __restrict__ xbf,
    const float* __restrict__ Dp, __bf16* __restrict__ ybf)
{
    const int bidx = blockIdx.x;
    const int bc = bidx & 31, h2 = bidx >> 5;
    __shared__ __attribute__((aligned(16))) __bf16 Bsh[256 * 64];
    __shared__ __attribute__((aligned(16))) __bf16 xsh[32 * 256];
    __shared__ __attribute__((aligned(16))) __bf16 Gw[4][16 * 72];
    __shared__ float ash[256];
    const int t = threadIdx.x, w = t >> 6, lane = t & 63;
    const int fr = lane & 15, q = lane >> 4;

    // ---- stage Bsh once (bc-dependent)
    const __bf16* Bsrc = Bbf + (size_t)bc * 16384;
#pragma unroll
    for (int cc = 0; cc < 8; ++cc) {
        int s = w * 8 + cc;
        int row = s * 8 + (lane >> 3);
        int ch = (lane & 7) ^ ((lane >> 3) & 7);
        async_copy16(Bsrc + row * 64 + ch * 8, Bsh + s * 512);
    }
    // ---- stage xsh + ash for h0
    {
        const size_t bch0 = (size_t)bc * 32 + h2 * 2;
        const __bf16* xsrc = xdtT + bch0 * 8192;
#pragma unroll
        for (int cc = 0; cc < 4; ++cc) {
            int s = w * 4 + cc;
            int p = s * 2 + (lane >> 5);
            int cl = lane & 31;
            int ch = (cl & 24) | ((cl & 7) ^ (p & 7));
            async_copy16(xsrc + p * 256 + ch * 8, xsh + s * 512);
        }
        ash[t] = acum[bch0 * 256 + t];
    }

    for (int hh = 0; hh < 2; ++hh) {
        const int h = h2 * 2 + hh;
        const size_t bch = (size_t)bc * 32 + h;
        __syncthreads();   // staging + ash visible (drains async)

        bf16x8 cf[4][2], pf[2][2];
        float ei4[4];
#pragma unroll
        for (int s4 = 0; s4 < 4; ++s4) {
            int i = (w + 4 * s4) * 16 + fr;
            const __bf16* cp = Cbf + ((size_t)bc * 256 + i) * 64 + q * 8;
            cf[s4][0] = *(const bf16x8*)cp;
            cf[s4][1] = *(const bf16x8*)(cp + 32);
            ei4[s4] = __expf(ash[i]);
        }
#pragma unroll
        for (int mt = 0; mt < 2; ++mt) {
            const __bf16* pp = prevbf + bch * 2048 + (size_t)(mt * 16 + fr) * 64 + q * 8;
            pf[mt][0] = *(const bf16x8*)pp;
            pf[mt][1] = *(const bf16x8*)(pp + 32);
        }
        float ai[4][4];
#pragma unroll
        for (int s4 = 0; s4 < 4; ++s4)
#pragma unroll
            for (int r = 0; r < 4; ++r)
                ai[s4][r] = ash[(w + 4 * s4) * 16 + q * 4 + r];

        f32x4 acc[4][2] = {};

#pragma unroll
        for (int jt = 0; jt < 4; ++jt) {
            bf16x8 bb[4][2], xa[2][2];
#pragma unroll
            for (int nt = 0; nt < 4; ++nt) {
                int j = jt * 64 + nt * 16 + fr;
#pragma unroll
                for (int ks = 0; ks < 2; ++ks) {
                    int ch = (q + 4 * ks) ^ (fr & 7);
                    bb[nt][ks] = *(const bf16x8*)&Bsh[j * 64 + ch * 8];
                }
            }
#pragma unroll
            for (int mt = 0; mt < 2; ++mt) {
                int p = mt * 16 + fr;
#pragma unroll
                for (int ks = 0; ks < 2; ++ks) {
                    int ch = 8 * jt + ((q + 4 * ks) ^ (p & 7));
                    xa[mt][ks] = *(const bf16x8*)&xsh[p * 256 + ch * 8];
                }
            }
#pragma unroll
            for (int s4 = 0; s4 < 4; ++s4) {
                int si = w + 4 * s4;
                if (si < 4 * jt) continue;
                f32x4 sreg[4];
#pragma unroll
                for (int nt = 0; nt < 4; ++nt) {
                    f32x4 z = {};
                    z = MFMA16(cf[s4][0], bb[nt][0], z);
                    z = MFMA16(cf[s4][1], bb[nt][1], z);
                    sreg[nt] = z;
                }
#pragma unroll
                for (int nt = 0; nt < 4; ++nt) {
                    int j = jt * 64 + nt * 16 + fr;
                    float aj = ash[j];
#pragma unroll
                    for (int r = 0; r < 4; ++r) {
                        int i = si * 16 + q * 4 + r;
                        float v = (j <= i) ? sreg[nt][r] * __expf(ai[s4][r] - aj) : 0.f;
                        Gw[w][(q * 4 + r) * 72 + nt * 16 + fr] = (__bf16)v;
                    }
                }
                bf16x8 g0 = *(const bf16x8*)&Gw[w][fr * 72 + q * 8];
                bf16x8 g1 = *(const bf16x8*)&Gw[w][fr * 72 + 32 + q * 8];
#pragma unroll
                for (int mt = 0; mt < 2; ++mt) {
                    acc[s4][mt] = MFMA16(xa[mt][0], g0, acc[s4][mt]);
                    acc[s4][mt] = MFMA16(xa[mt][1], g1, acc[s4][mt]);
                }
            }
        }
        __syncthreads();   // all xsh/ash reads done

        if (hh == 0) {     // issue h1 staging; overlaps h0 off-term+epilogue
            const size_t bch1 = bch + 1;
            const __bf16* xsrc = xdtT + bch1 * 8192;
#pragma unroll
            for (int cc = 0; cc < 4; ++cc) {
                int s = w * 4 + cc;
                int p = s * 2 + (lane >> 5);
                int cl = lane & 31;
                int ch = (cl & 24) | ((cl & 7) ^ (p & 7));
                async_copy16(xsrc + p * 256 + ch * 8, xsh + s * 512);
            }
            ash[t] = acum[bch1 * 256 + t];
        }

        // ---- off-term (registers only)
#pragma unroll
        for (int s4 = 0; s4 < 4; ++s4) {
#pragma unroll
            for (int ks = 0; ks < 2; ++ks) {
                bf16x8 ce;
#pragma unroll
                for (int e = 0; e < 8; ++e)
                    ce[e] = (__bf16)((float)cf[s4][ks][e] * ei4[s4]);
#pragma unroll
                for (int mt = 0; mt < 2; ++mt)
                    acc[s4][mt] = MFMA16(pf[mt][ks], ce, acc[s4][mt]);
            }
        }

        // ---- epilogue: + x*D, bf16x4 stores
        const float Dv = Dp[h];
#pragma unroll
        for (int s4 = 0; s4 < 4; ++s4) {
            int i = (w + 4 * s4) * 16 + fr;
            size_t row = (size_t)bc * 256 + i;
#pragma unroll
            for (int mt = 0; mt < 2; ++mt) {
                int p0 = mt * 16 + q * 4;
                bf16x4 xv = *(const bf16x4*)&xbf[row * 1024 + h * 32 + p0];
                bf16x4 o;
#pragma unroll
                for (int e = 0; e < 4; ++e)
                    o[e] = (__bf16)(acc[s4][mt][e] + (float)xv[e] * Dv);
                *(bf16x4*)&ybf[row * 1024 + h * 32 + p0] = o;
            }
        }
    }
}

// ---------------------------------------------------------------------------
extern "C" void kernel_launch(void* const* d_in, const int* in_sizes, int n_in,
                              void* d_out, int out_size, void* d_ws, size_t ws_size,
                              hipStream_t stream)
{
    (void)in_sizes; (void)n_in; (void)out_size;
    const float* u       = (const float*)d_in[0];
    const float* W_in    = (const float*)d_in[1];
    const float* dt_bias = (const float*)d_in[2];
    const float* A_log   = (const float*)d_in[3];
    const float* Dp      = (const float*)d_in[4];
    const float* W_out   = (const float*)d_in[5];
    float* out = (float*)d_out;

    if (ws_size < 72679424) return;

    char* ws = (char*)d_ws;
    __bf16* u_bf    = (__bf16*)(ws);                  // 16,777,216 (reused as ybf)
    __bf16* win_bf  = (__bf16*)(ws + 16777216);       //  2,424,832
    __bf16* wout_bf = (__bf16*)(ws + 19202048);       //  2,097,152
    __bf16* xbf     = (__bf16*)(ws + 21299200);       // 16,777,216
    float*  dtz     = (float*) (ws + 38076416);       //  1,048,576
    float*  acum    = (float*) (ws + 39124992);       //  1,048,576
    __bf16* xdtT    = (__bf16*)(ws + 40173568);       // 16,777,216
    float*  states  = (float*) (ws + 56950784);       //  8,388,608
    __bf16* prevbf  = (__bf16*)(ws + 65339392);       //  4,194,304
    __bf16* Bbf     = (__bf16*)(ws + 69533696);       //  1,048,576
    __bf16* Cbf     = (__bf16*)(ws + 70582272);       //  1,048,576
    __bf16* BbfT    = (__bf16*)(ws + 71630848);       //  1,048,576

    cvt_all<<<10400, 256, 0, stream>>>(u, u_bf, W_in, win_bf, W_out, wout_bf);

    gemm_fused<<<dim3(128, 10), 256, 0, stream>>>(u_bf, win_bf, 1024, 1184, 1,
                                                  nullptr, xbf, Bbf, Cbf, BbfT, dtz);

    middle_kernel<<<dim3(16, 16, 2), 256, 0, stream>>>(dtz, dt_bias, A_log, xbf,
                                                       BbfT, acum, xdtT, states);
    scan_kernel<<<512, 256, 0, stream>>>(states, acum, prevbf);

    __bf16* ybf = u_bf;  // u_bf dead after gemm1
    y_kernel<<<512, 256, 0, stream>>>(Bbf, Cbf, acum, xdtT, prevbf,
                                      xbf, Dp, ybf);

    gemm_fused<<<dim3(128, 8), 256, 0, stream>>>(ybf, wout_bf, 1024, 1024, 0,
                                                 out, nullptr, nullptr, nullptr,
                                                 nullptr, nullptr);
}

// Round 11
// 205.144 us; speedup vs baseline: 1.0653x; 1.0653x over previous
//
#include <hip/hip_runtime.h>
#include <hip/hip_bf16.h>
#include <stdint.h>

// ---------------------------------------------------------------------------
// SSD (Mamba-2 chunked scan) B=2, L=4096, DM=1024, NH=32, HD=32, DS=64, CS=256
// R11: y_kernel reverted to R8's 1-head form (R10's 2-head fusion blew VGPR
// 68->128 + LDS 58KB -> occupancy collapse + conflicts). middle keeps the
// 2-head BbfT-stage-once form (counters clean, halves staging traffic).
// gemm = R8 verbatim (BK=32 64x128, measured best).
// ---------------------------------------------------------------------------

typedef __bf16 bf16x8 __attribute__((ext_vector_type(8)));
typedef __bf16 bf16x4 __attribute__((ext_vector_type(4)));
typedef float  f32x4  __attribute__((ext_vector_type(4)));

#define MFMA16(a, b, c) __builtin_amdgcn_mfma_f32_16x16x32_bf16((a), (b), (c), 0, 0, 0)

__device__ __forceinline__ void async_copy16(const __bf16* g, __bf16* l) {
    __builtin_amdgcn_global_load_lds((const __attribute__((address_space(1))) void*)g,
                                     (__attribute__((address_space(3))) void*)l,
                                     16, 0, 0);
}

// ---------------------------------------------------------------------------
// fused fp32->bf16 convert for u, W_in, W_out
// ---------------------------------------------------------------------------
__global__ void cvt_all(const float* __restrict__ u, __bf16* __restrict__ ub,
                        const float* __restrict__ wi, __bf16* __restrict__ wib,
                        const float* __restrict__ wo, __bf16* __restrict__ wob)
{
    long i = ((long)blockIdx.x * 256 + threadIdx.x) * 4;
    const float* src; __bf16* dst; long off;
    if (i < 8388608)        { src = u;  dst = ub;  off = i; }
    else if (i < 9601024)   { src = wi; dst = wib; off = i - 8388608; }
    else if (i < 10649600)  { src = wo; dst = wob; off = i - 9601024; }
    else return;
    float4 v = *(const float4*)(src + off);
    bf16x4 o;
    o[0] = (__bf16)v.x; o[1] = (__bf16)v.y; o[2] = (__bf16)v.z; o[3] = (__bf16)v.w;
    *(bf16x4*)(dst + off) = o;
}

// ---------------------------------------------------------------------------
// GEMM core: 64M x 128N tile, BK=32 (R8 verbatim — measured 40.9us, 18MB
// FETCH, 39% occupancy, ~0 conflicts).
// ---------------------------------------------------------------------------
__global__ __launch_bounds__(256) void gemm_fused(
    const __bf16* __restrict__ A, const __bf16* __restrict__ Bt,
    int K, int Nrows, int mode,
    float* __restrict__ Cout, __bf16* __restrict__ xbf,
    __bf16* __restrict__ Bbf, __bf16* __restrict__ Cbf,
    __bf16* __restrict__ BbfT, float* __restrict__ dtz)
{
    __shared__ __attribute__((aligned(16))) __bf16 smem[6144];
    __bf16* As = smem;            // 64*32 = 2048
    __bf16* Bs = smem + 2048;     // 128*32 = 4096
    const int tid = threadIdx.x;
    const int m0 = blockIdx.x * 64;        // M-fast: same-A blocks share XCD
    const int n0 = blockIdx.y * 128;
    const int w = tid >> 6, lane = tid & 63;
    const int fr = lane & 15, quad = lane >> 4;
    const int sw = quad ^ ((fr >> 1) & 3);         // fragment-read position

    const int lr  = lane >> 2;                      // row within 16-row group
    const int lc8 = (((lane & 3) ^ ((lane >> 3) & 3))) * 8;  // swizzled chunk
    const int ra  = m0 + w * 16 + lr;               // A: wave stages 16 rows
    const int rb0 = min(n0 + w * 32 + lr, Nrows - 1);
    const int rb1 = min(n0 + w * 32 + 16 + lr, Nrows - 1);
    const __bf16* aP  = A + (size_t)ra * K + lc8;
    const __bf16* bP0 = Bt + (size_t)rb0 * K + lc8;
    const __bf16* bP1 = Bt + (size_t)rb1 * K + lc8;
    __bf16* dA  = As + w * 512;
    __bf16* dB0 = Bs + w * 1024;
    __bf16* dB1 = Bs + w * 1024 + 512;

    f32x4 acc[4][2] = {};

    for (int kt = 0; kt < K; kt += 32) {
        async_copy16(aP + kt, dA);
        async_copy16(bP0 + kt, dB0);
        async_copy16(bP1 + kt, dB1);
        __syncthreads();
        bf16x8 af[4], bfv[2];
#pragma unroll
        for (int a = 0; a < 4; ++a)
            af[a] = *(const bf16x8*)&As[(a * 16 + fr) * 32 + sw * 8];
#pragma unroll
        for (int b = 0; b < 2; ++b)
            bfv[b] = *(const bf16x8*)&Bs[(w * 32 + b * 16 + fr) * 32 + sw * 8];
#pragma unroll
        for (int a = 0; a < 4; ++a)
#pragma unroll
            for (int b = 0; b < 2; ++b)
                acc[a][b] = MFMA16(af[a], bfv[b], acc[a][b]);
        __syncthreads();
    }

    const int rowb = quad * 4;
    if (mode == 0) {
#pragma unroll
        for (int a = 0; a < 4; ++a)
#pragma unroll
            for (int b = 0; b < 2; ++b) {
                int col = n0 + w * 32 + b * 16 + fr;
#pragma unroll
                for (int q = 0; q < 4; ++q) {
                    int row = m0 + a * 16 + rowb + q;
                    Cout[(size_t)row * 1024 + col] = acc[a][b][q];
                }
            }
    } else if (blockIdx.y < 8) {
#pragma unroll
        for (int a = 0; a < 4; ++a)
#pragma unroll
            for (int b = 0; b < 2; ++b) {
                int col = n0 + w * 32 + b * 16 + fr;
#pragma unroll
                for (int q = 0; q < 4; ++q) {
                    int row = m0 + a * 16 + rowb + q;
                    xbf[(size_t)row * 1024 + col] = (__bf16)acc[a][b][q];
                }
            }
    } else if (blockIdx.y == 8) {
        // B/C routing + LDS-transposed coalesced BbfT (64 n x 64 rows)
        __bf16* Btile = smem;   // 64 x 72 (K-loop done; smem free)
#pragma unroll
        for (int a = 0; a < 4; ++a)
#pragma unroll
            for (int b = 0; b < 2; ++b) {
                int cl = w * 32 + b * 16 + fr;
#pragma unroll
                for (int q = 0; q < 4; ++q) {
                    int row = m0 + a * 16 + rowb + q;
                    __bf16 v = (__bf16)acc[a][b][q];
                    if (cl < 64) {
                        Bbf[(size_t)row * 64 + cl] = v;
                        Btile[cl * 72 + (row - m0)] = v;
                    } else {
                        Cbf[(size_t)row * 64 + cl - 64] = v;
                    }
                }
            }
        __syncthreads();
        const size_t bcb = (size_t)(m0 >> 8) * 16384 + (m0 & 255);
        int n = tid >> 2, g = tid & 3;
#pragma unroll
        for (int it = 0; it < 2; ++it) {
            int jl = g * 16 + it * 8;
            bf16x8 v = *(const bf16x8*)&Btile[n * 72 + jl];
            *(bf16x8*)&BbfT[bcb + (size_t)n * 256 + jl] = v;
        }
    } else {
#pragma unroll
        for (int a = 0; a < 4; ++a)
#pragma unroll
            for (int b = 0; b < 2; ++b) {
                int cl = w * 32 + b * 16 + fr;
                if (cl < 32) {
#pragma unroll
                    for (int q = 0; q < 4; ++q) {
                        int row = m0 + a * 16 + rowb + q;
                        dtz[(size_t)row * 32 + cl] = acc[a][b][q];
                    }
                }
            }
    }
}

// ---------------------------------------------------------------------------
// middle: fused prep + xdtT + states, 2 heads per block (BbfT staged once).
// ---------------------------------------------------------------------------
__global__ __launch_bounds__(256) void middle_kernel(
    const float* __restrict__ dtz, const float* __restrict__ dt_bias,
    const float* __restrict__ A_log, const __bf16* __restrict__ xbf,
    const __bf16* __restrict__ BbfT,
    float* __restrict__ acum_out, __bf16* __restrict__ xdtT,
    float* __restrict__ states)
{
    const int h2 = blockIdx.x, c = blockIdx.y, b = blockIdx.z;
    const size_t bc = (size_t)b * 16 + c;
    __shared__ __bf16 tile[256][33];
    __shared__ __attribute__((aligned(16))) __bf16 xdecT[32 * 264];
    __shared__ __attribute__((aligned(16))) __bf16 Bsh2[64 * 256];
    __shared__ float dts[256], decs[256], wsum[4];
    const int t = threadIdx.x, wave = t >> 6, lane = t & 63;

    {   // stage BbfT[bc] once (32 KB), chunk-swizzled: pos p holds chunk p^(n&7)
        const __bf16* src = BbfT + bc * 16384;
#pragma unroll
        for (int cc = 0; cc < 8; ++cc) {
            int s = wave * 8 + cc;
            int n = s * 2 + (lane >> 5);
            int jc = (lane & 31) ^ (n & 7);
            async_copy16(src + n * 256 + jc * 8, Bsh2 + s * 512);
        }
    }

    for (int hh = 0; hh < 2; ++hh) {
        const int h = h2 * 2 + hh;
        const size_t bch = bc * 32 + h;

        float z = dtz[(bc * 256 + t) * 32 + h] + dt_bias[h];
        float dtv = (z > 20.f) ? z : log1pf(expf(z));
        float Av = -expf(A_log[h]);
        float val = dtv * Av;
        dts[t] = dtv;
#pragma unroll
        for (int off = 1; off < 64; off <<= 1) {
            float nv = __shfl_up(val, off, 64);
            if (lane >= off) val += nv;
        }
        if (lane == 63) wsum[wave] = val;
        __syncthreads();            // also drains Bsh2 staging on hh=0
        float basep = 0.f, tot = 0.f;
#pragma unroll
        for (int wv = 0; wv < 4; ++wv) {
            float s = wsum[wv];
            if (wv < wave) basep += s;
            tot += s;
        }
        val += basep;
        acum_out[bch * 256 + t] = val;
        decs[t] = __expf(tot - val);

#pragma unroll
        for (int it = 0; it < 4; ++it) {
            int id = it * 256 + t;
            int j = id >> 2, pg = id & 3;
            bf16x8 v = *(const bf16x8*)&xbf[(bc * 256 + j) * 1024 + h * 32 + pg * 8];
            float d = dts[j];
#pragma unroll
            for (int e = 0; e < 8; ++e) tile[j][pg * 8 + e] = (__bf16)((float)v[e] * d);
        }
        __syncthreads();

#pragma unroll
        for (int it = 0; it < 4; ++it) {
            int id = it * 256 + t;
            int p = id >> 5, jg = id & 31;
            bf16x8 o, od;
#pragma unroll
            for (int e = 0; e < 8; ++e) {
                __bf16 v = tile[jg * 8 + e][p];
                o[e] = v;
                od[e] = (__bf16)((float)v * decs[jg * 8 + e]);
            }
            *(bf16x8*)&xdtT[bch * 8192 + p * 256 + jg * 8] = o;
            *(bf16x8*)&xdecT[p * 264 + jg * 8] = od;
        }
        __syncthreads();

        const int fr = lane & 15, quad = lane >> 4, fk = quad * 8;
        const int mt = wave >> 1, ntb = (wave & 1) * 2;
        f32x4 acc[2] = {};
#pragma unroll
        for (int ks = 0; ks < 8; ++ks) {
            bf16x8 af = *(const bf16x8*)&xdecT[(mt * 16 + fr) * 264 + ks * 32 + fk];
#pragma unroll
            for (int nb = 0; nb < 2; ++nb) {
                int n = (ntb + nb) * 16 + fr;
                int ch = (ks * 4 + quad) ^ (n & 7);
                bf16x8 bfv = *(const bf16x8*)&Bsh2[n * 256 + ch * 8];
                acc[nb] = MFMA16(af, bfv, acc[nb]);
            }
        }
        const int rowb = quad * 4;
#pragma unroll
        for (int nb = 0; nb < 2; ++nb)
#pragma unroll
            for (int q = 0; q < 4; ++q) {
                int p = mt * 16 + rowb + q;
                int n = (ntb + nb) * 16 + fr;
                states[bch * 2048 + p * 64 + n] = acc[nb][q];
            }
        __syncthreads();            // protect tile/dts/decs/wsum/xdecT reuse
    }
}

// ---------------------------------------------------------------------------
// scan: prev[b,c] = prev[b,c-1]*exp(alast[c-1]) + states[c-1]; bf16 out.
// ---------------------------------------------------------------------------
__global__ void scan_kernel(const float* __restrict__ states,
                            const float* __restrict__ acum,
                            __bf16* __restrict__ prevbf)
{
    int t = blockIdx.x * 256 + threadIdx.x;
    int n = t & 63, p = (t >> 6) & 31, h = (t >> 11) & 31, b = t >> 16;
    float s = 0.f;
    for (int c = 0; c < 16; ++c) {
        size_t bch = ((size_t)(b * 16 + c) * 32 + h);
        size_t off = bch * 2048 + (size_t)p * 64 + n;
        prevbf[off] = (__bf16)s;
        float dec = __expf(acum[bch * 256 + 255]);
        s = s * dec + states[off];
    }
}

// ---------------------------------------------------------------------------
// y: block=(b,c,h); 4 waves; wave w owns row-subtiles {w, w+4, w+8, w+12}.
// (R8 1-head version — VGPR ~84, measured clean.)
// ---------------------------------------------------------------------------
__global__ __launch_bounds__(256, 2) void y_kernel(
    const __bf16* __restrict__ Bbf, const __bf16* __restrict__ Cbf,
    const float* __restrict__ acum, const __bf16* __restrict__ xdtT,
    const __bf16* __restrict__ prevbf, const __bf16* __restrict__ xbf,
    const float* __restrict__ Dp, __bf16* __restrict__ ybf)
{
    const int bidx = blockIdx.x;
    const int bc = bidx & 31, h = bidx >> 5;
    const size_t bch = (size_t)bc * 32 + h;
    __shared__ __attribute__((aligned(16))) __bf16 Bsh[256 * 64];
    __shared__ __attribute__((aligned(16))) __bf16 xsh[32 * 256];
    __shared__ __attribute__((aligned(16))) __bf16 Gw[4][16 * 72];
    __shared__ float ash[256];
    const int t = threadIdx.x, w = t >> 6, lane = t & 63;
    const int fr = lane & 15, q = lane >> 4;

    const __bf16* Bsrc = Bbf + (size_t)bc * 16384;
#pragma unroll
    for (int cc = 0; cc < 8; ++cc) {
        int s = w * 8 + cc;
        int row = s * 8 + (lane >> 3);
        int ch = (lane & 7) ^ ((lane >> 3) & 7);
        async_copy16(Bsrc + row * 64 + ch * 8, Bsh + s * 512);
    }
    const __bf16* xsrc = xdtT + bch * 8192;
#pragma unroll
    for (int cc = 0; cc < 4; ++cc) {
        int s = w * 4 + cc;
        int p = s * 2 + (lane >> 5);
        int cl = lane & 31;
        int ch = (cl & 24) | ((cl & 7) ^ (p & 7));
        async_copy16(xsrc + p * 256 + ch * 8, xsh + s * 512);
    }
    ash[t] = acum[bch * 256 + t];
    __syncthreads();

    bf16x8 cf[4][2], pf[2][2];
    float ei4[4];
#pragma unroll
    for (int s4 = 0; s4 < 4; ++s4) {
        int i = (w + 4 * s4) * 16 + fr;
        const __bf16* cp = Cbf + ((size_t)bc * 256 + i) * 64 + q * 8;
        cf[s4][0] = *(const bf16x8*)cp;
        cf[s4][1] = *(const bf16x8*)(cp + 32);
        ei4[s4] = __expf(ash[i]);
    }
#pragma unroll
    for (int mt = 0; mt < 2; ++mt) {
        const __bf16* pp = prevbf + bch * 2048 + (size_t)(mt * 16 + fr) * 64 + q * 8;
        pf[mt][0] = *(const bf16x8*)pp;
        pf[mt][1] = *(const bf16x8*)(pp + 32);
    }
    float ai[4][4];
#pragma unroll
    for (int s4 = 0; s4 < 4; ++s4)
#pragma unroll
        for (int r = 0; r < 4; ++r)
            ai[s4][r] = ash[(w + 4 * s4) * 16 + q * 4 + r];

    f32x4 acc[4][2] = {};

#pragma unroll
    for (int jt = 0; jt < 4; ++jt) {
        bf16x8 bb[4][2], xa[2][2];
#pragma unroll
        for (int nt = 0; nt < 4; ++nt) {
            int j = jt * 64 + nt * 16 + fr;
#pragma unroll
            for (int ks = 0; ks < 2; ++ks) {
                int ch = (q + 4 * ks) ^ (fr & 7);
                bb[nt][ks] = *(const bf16x8*)&Bsh[j * 64 + ch * 8];
            }
        }
#pragma unroll
        for (int mt = 0; mt < 2; ++mt) {
            int p = mt * 16 + fr;
#pragma unroll
            for (int ks = 0; ks < 2; ++ks) {
                int ch = 8 * jt + ((q + 4 * ks) ^ (p & 7));
                xa[mt][ks] = *(const bf16x8*)&xsh[p * 256 + ch * 8];
            }
        }
#pragma unroll
        for (int s4 = 0; s4 < 4; ++s4) {
            int si = w + 4 * s4;
            if (si < 4 * jt) continue;
            f32x4 sreg[4];
#pragma unroll
            for (int nt = 0; nt < 4; ++nt) {
                f32x4 z = {};
                z = MFMA16(cf[s4][0], bb[nt][0], z);
                z = MFMA16(cf[s4][1], bb[nt][1], z);
                sreg[nt] = z;
            }
#pragma unroll
            for (int nt = 0; nt < 4; ++nt) {
                int j = jt * 64 + nt * 16 + fr;
                float aj = ash[j];
#pragma unroll
                for (int r = 0; r < 4; ++r) {
                    int i = si * 16 + q * 4 + r;
                    float v = (j <= i) ? sreg[nt][r] * __expf(ai[s4][r] - aj) : 0.f;
                    Gw[w][(q * 4 + r) * 72 + nt * 16 + fr] = (__bf16)v;
                }
            }
            bf16x8 g0 = *(const bf16x8*)&Gw[w][fr * 72 + q * 8];
            bf16x8 g1 = *(const bf16x8*)&Gw[w][fr * 72 + 32 + q * 8];
#pragma unroll
            for (int mt = 0; mt < 2; ++mt) {
                acc[s4][mt] = MFMA16(xa[mt][0], g0, acc[s4][mt]);
                acc[s4][mt] = MFMA16(xa[mt][1], g1, acc[s4][mt]);
            }
        }
    }

#pragma unroll
    for (int s4 = 0; s4 < 4; ++s4) {
#pragma unroll
        for (int ks = 0; ks < 2; ++ks) {
            bf16x8 ce;
#pragma unroll
            for (int e = 0; e < 8; ++e)
                ce[e] = (__bf16)((float)cf[s4][ks][e] * ei4[s4]);
#pragma unroll
            for (int mt = 0; mt < 2; ++mt)
                acc[s4][mt] = MFMA16(pf[mt][ks], ce, acc[s4][mt]);
        }
    }

    const float Dv = Dp[h];
#pragma unroll
    for (int s4 = 0; s4 < 4; ++s4) {
        int i = (w + 4 * s4) * 16 + fr;
        size_t row = (size_t)bc * 256 + i;
#pragma unroll
        for (int mt = 0; mt < 2; ++mt) {
            int p0 = mt * 16 + q * 4;
            bf16x4 xv = *(const bf16x4*)&xbf[row * 1024 + h * 32 + p0];
            bf16x4 o;
#pragma unroll
            for (int e = 0; e < 4; ++e)
                o[e] = (__bf16)(acc[s4][mt][e] + (float)xv[e] * Dv);
            *(bf16x4*)&ybf[row * 1024 + h * 32 + p0] = o;
        }
    }
}

// ---------------------------------------------------------------------------
extern "C" void kernel_launch(void* const* d_in, const int* in_sizes, int n_in,
                              void* d_out, int out_size, void* d_ws, size_t ws_size,
                              hipStream_t stream)
{
    (void)in_sizes; (void)n_in; (void)out_size;
    const float* u       = (const float*)d_in[0];
    const float* W_in    = (const float*)d_in[1];
    const float* dt_bias = (const float*)d_in[2];
    const float* A_log   = (const float*)d_in[3];
    const float* Dp      = (const float*)d_in[4];
    const float* W_out   = (const float*)d_in[5];
    float* out = (float*)d_out;

    if (ws_size < 72679424) return;

    char* ws = (char*)d_ws;
    __bf16* u_bf    = (__bf16*)(ws);                  // 16,777,216 (reused as ybf)
    __bf16* win_bf  = (__bf16*)(ws + 16777216);       //  2,424,832
    __bf16* wout_bf = (__bf16*)(ws + 19202048);       //  2,097,152
    __bf16* xbf     = (__bf16*)(ws + 21299200);       // 16,777,216
    float*  dtz     = (float*) (ws + 38076416);       //  1,048,576
    float*  acum    = (float*) (ws + 39124992);       //  1,048,576
    __bf16* xdtT    = (__bf16*)(ws + 40173568);       // 16,777,216
    float*  states  = (float*) (ws + 56950784);       //  8,388,608
    __bf16* prevbf  = (__bf16*)(ws + 65339392);       //  4,194,304
    __bf16* Bbf     = (__bf16*)(ws + 69533696);       //  1,048,576
    __bf16* Cbf     = (__bf16*)(ws + 70582272);       //  1,048,576
    __bf16* BbfT    = (__bf16*)(ws + 71630848);       //  1,048,576

    cvt_all<<<10400, 256, 0, stream>>>(u, u_bf, W_in, win_bf, W_out, wout_bf);

    gemm_fused<<<dim3(128, 10), 256, 0, stream>>>(u_bf, win_bf, 1024, 1184, 1,
                                                  nullptr, xbf, Bbf, Cbf, BbfT, dtz);

    middle_kernel<<<dim3(16, 16, 2), 256, 0, stream>>>(dtz, dt_bias, A_log, xbf,
                                                       BbfT, acum, xdtT, states);
    scan_kernel<<<512, 256, 0, stream>>>(states, acum, prevbf);

    __bf16* ybf = u_bf;  // u_bf dead after gemm1
    y_kernel<<<1024, 256, 0, stream>>>(Bbf, Cbf, acum, xdtT, prevbf,
                                       xbf, Dp, ybf);

    gemm_fused<<<dim3(128, 8), 256, 0, stream>>>(ybf, wout_bf, 1024, 1024, 0,
                                                 out, nullptr, nullptr, nullptr,
                                                 nullptr, nullptr);
}